// Round 13
// baseline (242.444 us; speedup 1.0000x reference)
//
#include <hip/hip_runtime.h>

typedef unsigned short u16;
typedef unsigned int   u32;
typedef __bf16  bf16x8 __attribute__((ext_vector_type(8)));
typedef __bf16  bf16x4_t __attribute__((ext_vector_type(4)));
typedef float   f32x4  __attribute__((ext_vector_type(4)));
typedef float   f32x2  __attribute__((ext_vector_type(2)));

struct Ptrs { const void* p[13]; };

extern "C" __device__ float __ocml_native_exp2_f32(float);  // -> v_exp_f32

// ---------- bf16 <-> f32 helpers ----------
__device__ __forceinline__ float bf2f(u16 u) {
    union { unsigned int i; float f; } c; c.i = ((unsigned int)u) << 16; return c.f;
}
__device__ __forceinline__ u16 f2bf(float f) {
    union { float f; unsigned int i; } c; c.f = f;
    unsigned int u = c.i;
    unsigned int r = (u + 0x7fffu + ((u >> 16) & 1u)) >> 16;  // RNE
    return (u16)r;
}

__device__ __forceinline__ float wave_sum(float x) {
#pragma unroll
    for (int m = 32; m >= 1; m >>= 1) x += __shfl_xor(x, m);
    return x;
}

// async global->LDS 16B/lane. LDS dest is wave-uniform base + lane*16.
__device__ __forceinline__ void g2l16(const u16* g, u16* l) {
    __builtin_amdgcn_global_load_lds(
        (__attribute__((address_space(1))) void*)g,
        (__attribute__((address_space(3))) void*)l, 16, 0, 0);
}

// dtype sniff: 32 dwords of qkv_w (bf16 low-half exponent distribution).
__device__ __forceinline__ int sniff_bf16(const u32* __restrict__ w) {
    int cnt = 0;
    for (int i = 0; i < 32; ++i) {
        u16 lo = (u16)(w[i] & 0xFFFFu);
        int e = (lo >> 7) & 0xFF;
        cnt += (e >= 117 && e <= 123) ? 1 : 0;
    }
    return (cnt >= 16) ? 1 : 0;
}

// ---------------------------------------------------------------------------
// Fused: weight canonicalization (blocks < 867) + x-conversion/LN1 (rest).
// ---------------------------------------------------------------------------
__global__ __launch_bounds__(256) void k_cvt_ln1(Ptrs ps,
                                                 u16* __restrict__ cw,
                                                 int* __restrict__ flagp,
                                                 u16* __restrict__ cx,
                                                 u16* __restrict__ h)
{
    const int flag = sniff_bf16((const u32*)ps.p[3]);
    if (blockIdx.x == 0 && threadIdx.x == 0) *flagp = flag;

    if (blockIdx.x < 867) {
        // ---- weight conversion path ----
        const int cum[13] = {0,48,96,55392,55536,73968,74016,74064,74112,
                             147840,148032,221760,221808};
        const int off[12] = {0,384,768,443136,444288,591744,
                             592128,592512,592896,1182720,1184256,1774080};
        int c = blockIdx.x * 256 + threadIdx.x;
        if (c >= 221808) return;
        int seg = 0;
#pragma unroll
        for (int i = 1; i < 12; ++i) seg += (c >= cum[i]) ? 1 : 0;
        int e = (c - cum[seg]) * 8;
        u16* dst = cw + off[seg] + e;
        if (flag) {
            *(uint4*)dst = *((const uint4*)ps.p[seg + 1] + (e >> 3));
        } else {
            const float* s = (const float*)ps.p[seg + 1] + e;
            u16 tmp[8];
#pragma unroll
            for (int t = 0; t < 8; ++t) tmp[t] = f2bf(s[t]);
            *(uint4*)dst = *(const uint4*)tmp;
        }
        return;
    }

    // ---- LN1 + x-canonicalization path ----
    const int wid = threadIdx.x >> 6, lane = threadIdx.x & 63;
    const int row = (blockIdx.x - 867) * 4 + wid;
    const int e0 = lane * 6;
    float v[6]; u16 raw[6];
    float gv[6], bv[6];
    if (flag) {
        const u16* p = (const u16*)ps.p[0] + (size_t)row * 384 + e0;
        u32 w0 = *(const u32*)(p);
        u32 w1 = *(const u32*)(p + 2);
        u32 w2 = *(const u32*)(p + 4);
        raw[0] = (u16)w0; raw[1] = (u16)(w0 >> 16);
        raw[2] = (u16)w1; raw[3] = (u16)(w1 >> 16);
        raw[4] = (u16)w2; raw[5] = (u16)(w2 >> 16);
#pragma unroll
        for (int t = 0; t < 6; t++) v[t] = bf2f(raw[t]);
        const u16* gp = (const u16*)ps.p[1] + e0;
        const u16* bp = (const u16*)ps.p[2] + e0;
#pragma unroll
        for (int t = 0; t < 6; t++) { gv[t] = bf2f(gp[t]); bv[t] = bf2f(bp[t]); }
    } else {
        const float* p = (const float*)ps.p[0] + (size_t)row * 384 + e0;
        f32x2 a0 = *(const f32x2*)(p);
        f32x2 a1 = *(const f32x2*)(p + 2);
        f32x2 a2 = *(const f32x2*)(p + 4);
        v[0] = a0[0]; v[1] = a0[1]; v[2] = a1[0];
        v[3] = a1[1]; v[4] = a2[0]; v[5] = a2[1];
#pragma unroll
        for (int t = 0; t < 6; t++) raw[t] = f2bf(v[t]);
        const float* gp = (const float*)ps.p[1] + e0;
        const float* bp = (const float*)ps.p[2] + e0;
#pragma unroll
        for (int t = 0; t < 6; t++) { gv[t] = gp[t]; bv[t] = bp[t]; }
    }
    u32* pc = (u32*)(cx + (size_t)row * 384 + e0);
    pc[0] = (u32)raw[0] | ((u32)raw[1] << 16);
    pc[1] = (u32)raw[2] | ((u32)raw[3] << 16);
    pc[2] = (u32)raw[4] | ((u32)raw[5] << 16);
    float s = 0.f;
#pragma unroll
    for (int t = 0; t < 6; t++) s += v[t];
    const float mu = wave_sum(s) * (1.0f / 384.0f);
    float vs = 0.f;
#pragma unroll
    for (int t = 0; t < 6; t++) { float d = v[t] - mu; vs += d * d; }
    const float var = wave_sum(vs) * (1.0f / 384.0f);
    const float rs = rsqrtf(var + 1e-5f);
    u16 ow[6];
#pragma unroll
    for (int t = 0; t < 6; t++)
        ow[t] = f2bf((v[t] - mu) * rs * gv[t] + bv[t]);
    u32* po = (u32*)(h + (size_t)row * 384 + e0);
    po[0] = (u32)ow[0] | ((u32)ow[1] << 16);
    po[1] = (u32)ow[2] | ((u32)ow[3] << 16);
    po[2] = (u32)ow[4] | ((u32)ow[5] << 16);
}

// ---------------------------------------------------------------------------
// Core MFMA GEMM 128x128, 8-WAVE version (512 threads): each wave owns
// 64x32 (acc[4][2] = 32 VGPR). Full 2048-thread/CU occupancy.
// SWAP=true swaps mfma operand order (quad axis = B-row).
// ---------------------------------------------------------------------------
template <bool SWAP = false>
__device__ __forceinline__ void gemm_core_128_w8(const u16* __restrict__ A,
                                                 const u16* __restrict__ B,
                                                 int K, int m0, int n0,
                                                 f32x4 (&acc)[4][2])
{
    __shared__ __align__(16) u16 As[128 * 64];
    __shared__ __align__(16) u16 Bs[128 * 64];

    const int tid  = threadIdx.x;
    const int lane = tid & 63;
    const int wid  = tid >> 6;           // 0..7
    const int wm  = (wid >> 2) * 64;     // 0, 64
    const int wn  = (wid & 3) * 32;      // 0, 32, 64, 96
    const int l15 = lane & 15;
    const int g   = lane >> 4;
    const int srow   = lane >> 3;
    const int schunk = ((lane & 7) ^ srow) * 8;

    const u16* Abase = A + (size_t)(m0 + wid * 16 + srow) * K + schunk;
    const u16* Bbase = B + (size_t)(n0 + wid * 16 + srow) * K + schunk;

    for (int kk = 0; kk < K; kk += 64) {
        __syncthreads();
#pragma unroll
        for (int t = 0; t < 2; ++t) {
            g2l16(Abase + (size_t)t * 8 * K + kk, &As[(wid * 16 + t * 8) * 64]);
            g2l16(Bbase + (size_t)t * 8 * K + kk, &Bs[(wid * 16 + t * 8) * 64]);
        }
        __syncthreads();

#pragma unroll
        for (int ks = 0; ks < 2; ++ks) {
            const int p = ((ks * 4 + g) ^ (l15 & 7)) * 8;
            bf16x8 af[4], bfr[2];
#pragma unroll
            for (int i = 0; i < 4; i++)
                af[i] = __builtin_bit_cast(bf16x8,
                         *(const uint4*)&As[(wm + 16 * i + l15) * 64 + p]);
#pragma unroll
            for (int j = 0; j < 2; j++)
                bfr[j] = __builtin_bit_cast(bf16x8,
                         *(const uint4*)&Bs[(wn + 16 * j + l15) * 64 + p]);
#pragma unroll
            for (int i = 0; i < 4; i++)
#pragma unroll
                for (int j = 0; j < 2; j++) {
                    if (SWAP)
                        acc[i][j] = __builtin_amdgcn_mfma_f32_16x16x32_bf16(
                                        bfr[j], af[i], acc[i][j], 0, 0, 0);
                    else
                        acc[i][j] = __builtin_amdgcn_mfma_f32_16x16x32_bf16(
                                        af[i], bfr[j], acc[i][j], 0, 0, 0);
                }
        }
    }
}

// ---------------------------------------------------------------------------
// Core MFMA GEMM 128x64, 8-WAVE version (512 threads): per-wave 32x32,
// acc[2][2] = 16 VGPR. LDS 24 KB.
// ---------------------------------------------------------------------------
__device__ __forceinline__ void gemm_core_128x64_w8(const u16* __restrict__ A,
                                                    const u16* __restrict__ B,
                                                    int K, int m0, int n0,
                                                    f32x4 (&acc)[2][2])
{
    __shared__ __align__(16) u16 As[128 * 64];
    __shared__ __align__(16) u16 Bs[64 * 64];

    const int tid  = threadIdx.x;
    const int lane = tid & 63;
    const int wid  = tid >> 6;           // 0..7
    const int wm  = (wid >> 1) * 32;     // 0,32,64,96
    const int wn  = (wid & 1) * 32;      // 0,32
    const int l15 = lane & 15;
    const int g   = lane >> 4;
    const int srow   = lane >> 3;
    const int schunk = ((lane & 7) ^ srow) * 8;

    const u16* Abase = A + (size_t)(m0 + wid * 16 + srow) * K + schunk;
    const u16* Bbase = B + (size_t)(n0 + wid * 8 + srow) * K + schunk;

    for (int kk = 0; kk < K; kk += 64) {
        __syncthreads();
#pragma unroll
        for (int t = 0; t < 2; ++t)
            g2l16(Abase + (size_t)t * 8 * K + kk, &As[(wid * 16 + t * 8) * 64]);
        g2l16(Bbase + kk, &Bs[(wid * 8) * 64]);
        __syncthreads();

#pragma unroll
        for (int ks = 0; ks < 2; ++ks) {
            const int p = ((ks * 4 + g) ^ (l15 & 7)) * 8;
            bf16x8 af[2], bfr[2];
#pragma unroll
            for (int i = 0; i < 2; i++)
                af[i] = __builtin_bit_cast(bf16x8,
                         *(const uint4*)&As[(wm + 16 * i + l15) * 64 + p]);
#pragma unroll
            for (int j = 0; j < 2; j++)
                bfr[j] = __builtin_bit_cast(bf16x8,
                         *(const uint4*)&Bs[(wn + 16 * j + l15) * 64 + p]);
#pragma unroll
            for (int i = 0; i < 2; i++)
#pragma unroll
                for (int j = 0; j < 2; j++)
                    acc[i][j] = __builtin_amdgcn_mfma_f32_16x16x32_bf16(
                                    af[i], bfr[j], acc[i][j], 0, 0, 0);
        }
    }
}

// ---------------- LayerNorm (bf16 in; used for LN2) ----------------
__global__ __launch_bounds__(256) void k_layernorm(const u16* __restrict__ in,
                                                   const u16* __restrict__ g,
                                                   const u16* __restrict__ b,
                                                   u16* __restrict__ out,
                                                   int nrows)
{
    const int wid = threadIdx.x >> 6, lane = threadIdx.x & 63;
    const int row = blockIdx.x * 4 + wid;
    if (row >= nrows) return;
    const int e0 = lane * 6;
    float v[6];
    const u16* p = in + (size_t)row * 384 + e0;
    u32 w0 = *(const u32*)(p);
    u32 w1 = *(const u32*)(p + 2);
    u32 w2 = *(const u32*)(p + 4);
    v[0] = bf2f((u16)w0); v[1] = bf2f((u16)(w0 >> 16));
    v[2] = bf2f((u16)w1); v[3] = bf2f((u16)(w1 >> 16));
    v[4] = bf2f((u16)w2); v[5] = bf2f((u16)(w2 >> 16));
    float s = 0.f;
#pragma unroll
    for (int t = 0; t < 6; t++) s += v[t];
    const float mu = wave_sum(s) * (1.0f / 384.0f);
    float vs = 0.f;
#pragma unroll
    for (int t = 0; t < 6; t++) { float d = v[t] - mu; vs += d * d; }
    const float var = wave_sum(vs) * (1.0f / 384.0f);
    const float rs = rsqrtf(var + 1e-5f);
    const u32* gg = (const u32*)(g + e0);
    const u32* bb = (const u32*)(b + e0);
    u32 gw[3] = {gg[0], gg[1], gg[2]};
    u32 bw[3] = {bb[0], bb[1], bb[2]};
    u16 ow[6];
#pragma unroll
    for (int t = 0; t < 6; t++) {
        u16 ge = (u16)(gw[t >> 1] >> ((t & 1) * 16));
        u16 be = (u16)(bw[t >> 1] >> ((t & 1) * 16));
        ow[t] = f2bf((v[t] - mu) * rs * bf2f(ge) + bf2f(be));
    }
    u32* po = (u32*)(out + (size_t)row * 384 + e0);
    po[0] = (u32)ow[0] | ((u32)ow[1] << 16);
    po[1] = (u32)ow[2] | ((u32)ow[3] << 16);
    po[2] = (u32)ow[4] | ((u32)ow[5] << 16);
}

// ---------------- QKV GEMM + bias + scatter; V written TRANSPOSED ----------
// 8-wave SWAP core: reg quad = output COLUMN (dh) axis -> q/k one aligned
// 8B store per (i,j); vT 4x scalar.
__global__ __launch_bounds__(512) void k_gemm_qkv(const u16* __restrict__ A,
                                                  const u16* __restrict__ W,
                                                  const u16* __restrict__ bias,
                                                  u16* __restrict__ q,
                                                  u16* __restrict__ kbuf,
                                                  u16* __restrict__ vT)
{
    const int id = blockIdx.x, slot = id & 7, idx = id >> 3;
    const int m0 = (slot * 16 + idx / 9) * 128;
    const int n0 = (idx % 9) * 128;
    f32x4 acc[4][2];
#pragma unroll
    for (int i = 0; i < 4; i++)
#pragma unroll
        for (int j = 0; j < 2; j++) acc[i][j] = f32x4{0.f, 0.f, 0.f, 0.f};
    gemm_core_128_w8<true>(A, W, 384, m0, n0, acc);
    const int lane = threadIdx.x & 63, wid = threadIdx.x >> 6;
    const int wm = (wid >> 2) * 64, wn = (wid & 3) * 32;
    const int l15 = lane & 15, rq = (lane >> 4) * 4;
#pragma unroll
    for (int i = 0; i < 4; i++) {
        const int gr = m0 + wm + 16 * i + l15;        // row on lane axis
        const int bb = gr >> 10, nn = gr & 1023;
#pragma unroll
        for (int j = 0; j < 2; j++) {
            const int gcb = n0 + wn + 16 * j + rq;    // col base on quad axis
            const int part = gcb / 384, rem = gcb % 384;
            const int head = rem >> 6, dhb = rem & 63;
            const int bh = bb * 6 + head;
            float vals[4];
#pragma unroll
            for (int r = 0; r < 4; r++) vals[r] = acc[i][j][r] + bf2f(bias[gcb + r]);
            if (part == 2) {
#pragma unroll
                for (int r = 0; r < 4; r++)
                    vT[((size_t)bh * 64 + dhb + r) * 1024 + nn] = f2bf(vals[r]);
            } else {
                u16* dst = part ? kbuf : q;
                u32 lo = (u32)f2bf(vals[0]) | ((u32)f2bf(vals[1]) << 16);
                u32 hi = (u32)f2bf(vals[2]) | ((u32)f2bf(vals[3]) << 16);
                uint2 pk; pk.x = lo; pk.y = hi;
                *(uint2*)&dst[((size_t)bh * 1024 + nn) * 64 + dhb] = pk;
            }
        }
    }
}

// ---------------------------------------------------------------------------
// Fused flash attention v9: double-buffered prefetch staging at CONSTANT
// LDS. KV tile shrunk 128->64 keys per iteration, freeing enough LDS to
// double-buffer BOTH K and V in the same 48K (Ks 2x8K + Vs 2x8K + Ps 16K)
// -> still 3 blocks/CU, 24 waves. Loop: issue g2l16 for tile t+1 into buf
// B, compute tile t from buf A, ONE barrier, swap. Same total barrier
// count as v7 (16), but each barrier's vmcnt drain lands after ~1400cy of
// MFMA/exp cover instead of right after issue (v7 exposed the full staging
// RTT every iteration -- why attn was flat across 12->24 waves/CU).
// Buffers are compile-time (explicit 2-step loop body; rule #20).
// ---------------------------------------------------------------------------
__global__ __launch_bounds__(512) void k_attn(const u16* __restrict__ q,
                                              const u16* __restrict__ kk,
                                              const u16* __restrict__ vT,
                                              u16* __restrict__ o)
{
    __shared__ __align__(16) u16 Ks0[64 * 64];
    __shared__ __align__(16) u16 Ks1[64 * 64];
    __shared__ __align__(16) u16 Vs0[64 * 64];
    __shared__ __align__(16) u16 Vs1[64 * 64];
    __shared__ __align__(16) u16 Ps[128 * 64];

    const int tid = threadIdx.x, lane = tid & 63, wid = tid >> 6;  // wid 0..7
    const int l15 = lane & 15, g = lane >> 4, q8 = g * 8;
    const int id = blockIdx.x;
    const int bh = (id & 7) * 12 + ((id >> 3) >> 3);
    const int q0 = ((id >> 3) & 7) * 128;
    const int wrow = wid * 16;                         // 16 q-rows per wave

    const u16* Q = q  + (size_t)bh * 65536;
    const u16* K = kk + (size_t)bh * 65536;
    const u16* V = vT + (size_t)bh * 65536;

    const int srow   = lane >> 3;
    const int schunk = ((lane & 7) ^ srow) * 8;
    const int rd0 = ((0 + g) ^ (l15 & 7)) * 8;
    const int rd1 = ((4 + g) ^ (l15 & 7)) * 8;
    int pcol[4];
#pragma unroll
    for (int ip = 0; ip < 4; ++ip)
        pcol[ip] = (((ip * 2 + (g >> 1)) ^ (l15 & 7)) * 8) + (g & 1) * 4;

    // per-iteration staging: each wave stages 8 K-rows + 8 V(dh)-rows
    const u16* Ksrc = K + (size_t)(wid * 8 + srow) * 64 + schunk;    // + kt*4096
    const u16* Vsrc = V + (size_t)(wid * 8 + srow) * 1024 + schunk;  // + kt*64
    u16* Kd0 = &Ks0[(wid * 8) * 64];
    u16* Kd1 = &Ks1[(wid * 8) * 64];
    u16* Vd0 = &Vs0[(wid * 8) * 64];
    u16* Vd1 = &Vs1[(wid * 8) * 64];

    // Q frags pre-scaled by 0.125*log2(e)
    bf16x8 aq[2];
#pragma unroll
    for (int ks = 0; ks < 2; ++ks) {
        bf16x8 t = __builtin_bit_cast(bf16x8,
            *(const uint4*)&Q[(size_t)(q0 + wrow + l15) * 64 + ks * 32 + q8]);
#pragma unroll
        for (int e = 0; e < 8; ++e)
            t[e] = (__bf16)((float)t[e] * 0.18033688f);
        aq[ks] = t;
    }

    f32x4 ob[4];
#pragma unroll
    for (int j = 0; j < 4; ++j) ob[j] = f32x4{0.f, 0.f, 0.f, 0.f};
    float lsum = 0.f;

    // one-tile compute (64 keys) from the given buffers
    auto compute = [&](const u16* Kbuf, const u16* Vbuf) {
        f32x4 st[4];
#pragma unroll
        for (int ip = 0; ip < 4; ++ip) st[ip] = f32x4{0.f, 0.f, 0.f, 0.f};
        __builtin_amdgcn_s_setprio(1);
#pragma unroll
        for (int ip = 0; ip < 4; ++ip) {
            int rbase = (ip * 16 + l15) * 64;
            bf16x8 bk0 = __builtin_bit_cast(bf16x8,
                *(const uint4*)&Kbuf[rbase + rd0]);
            bf16x8 bk1 = __builtin_bit_cast(bf16x8,
                *(const uint4*)&Kbuf[rbase + rd1]);
            st[ip] = __builtin_amdgcn_mfma_f32_16x16x32_bf16(
                        bk0, aq[0], st[ip], 0, 0, 0);
            st[ip] = __builtin_amdgcn_mfma_f32_16x16x32_bf16(
                        bk1, aq[1], st[ip], 0, 0, 0);
        }
        __builtin_amdgcn_s_setprio(0);

        float ps = 0.f;
#pragma unroll
        for (int ip = 0; ip < 4; ++ip)
#pragma unroll
            for (int r = 0; r < 4; ++r) {
                float p = __ocml_native_exp2_f32(st[ip][r]);
                st[ip][r] = p;
                ps += p;
            }
        lsum += ps;

#pragma unroll
        for (int ip = 0; ip < 4; ++ip) {
            bf16x4_t pk;
#pragma unroll
            for (int r = 0; r < 4; ++r) pk[r] = (__bf16)st[ip][r];
            *(bf16x4_t*)&Ps[(wrow + l15) * 64 + pcol[ip]] = pk;
        }

        __builtin_amdgcn_s_setprio(1);
#pragma unroll
        for (int ks = 0; ks < 2; ++ks) {
            const int rdo = ks ? rd1 : rd0;
            bf16x8 ap = __builtin_bit_cast(bf16x8,
                *(const uint4*)&Ps[(wrow + l15) * 64 + rdo]);
#pragma unroll
            for (int jv = 0; jv < 4; ++jv) {
                bf16x8 bv = __builtin_bit_cast(bf16x8,
                    *(const uint4*)&Vbuf[(jv * 16 + l15) * 64 + rdo]);
                ob[jv] = __builtin_amdgcn_mfma_f32_16x16x32_bf16(
                            ap, bv, ob[jv], 0, 0, 0);
            }
        }
        __builtin_amdgcn_s_setprio(0);
    };

    // prologue: stage tile 0 into buf 0
    g2l16(Ksrc, Kd0);
    g2l16(Vsrc, Vd0);
    __syncthreads();

#pragma unroll 1
    for (int k2 = 0; k2 < 8; ++k2) {
        // even tile (2*k2) in buf0; prefetch tile 2*k2+1 into buf1
        {
            int nt = 2 * k2 + 1;
            g2l16(Ksrc + (size_t)nt * 4096, Kd1);
            g2l16(Vsrc + (size_t)nt * 64, Vd1);
        }
        compute(Ks0, Vs0);
        __syncthreads();

        // odd tile (2*k2+1) in buf1; prefetch tile 2*k2+2 into buf0
        if (k2 < 7) {
            int nt = 2 * k2 + 2;
            g2l16(Ksrc + (size_t)nt * 4096, Kd0);
            g2l16(Vsrc + (size_t)nt * 64, Vd0);
        }
        compute(Ks1, Vs1);
        __syncthreads();
    }

    lsum += __shfl_xor(lsum, 16);
    lsum += __shfl_xor(lsum, 32);
    const int bb = bh / 6, hh = bh % 6;
#pragma unroll
    for (int r = 0; r < 4; ++r) {
        int src = (lane & 48) | (g * 4 + r);
        float linv = 1.0f / __shfl(lsum, src);
        int row = q0 + wrow + g * 4 + r;
#pragma unroll
        for (int jv = 0; jv < 4; ++jv) {
            int dh = jv * 16 + l15;
            o[((size_t)(bb * 1024 + row)) * 384 + hh * 64 + dh] =
                f2bf(ob[jv][r] * linv);
        }
    }
}

// ---------------- proj GEMM + bias + residual(cx) -> x1 bf16 ---------------
__global__ __launch_bounds__(512) void k_gemm_proj(const u16* __restrict__ A,
                                                   const u16* __restrict__ W,
                                                   const u16* __restrict__ bias,
                                                   const u16* __restrict__ xin,
                                                   u16* __restrict__ x1)
{
    const int id = blockIdx.x, slot = id & 7, idx = id >> 3;
    const int m0 = (slot * 16 + idx / 6) * 128;
    const int n0 = (idx % 6) * 64;
    f32x4 acc[2][2];
#pragma unroll
    for (int i = 0; i < 2; i++)
#pragma unroll
        for (int j = 0; j < 2; j++) acc[i][j] = f32x4{0.f, 0.f, 0.f, 0.f};
    gemm_core_128x64_w8(A, W, 384, m0, n0, acc);
    const int lane = threadIdx.x & 63, wid = threadIdx.x >> 6;
    const int wm = (wid >> 1) * 32, wn = (wid & 1) * 32;
    const int l15 = lane & 15, rq = (lane >> 4) * 4;
#pragma unroll
    for (int i = 0; i < 2; i++)
#pragma unroll
        for (int j = 0; j < 2; j++)
#pragma unroll
            for (int r = 0; r < 4; r++) {
                int gr = m0 + wm + 16 * i + rq + r;
                int gc = n0 + wn + 16 * j + l15;
                size_t ix = (size_t)gr * 384 + gc;
                x1[ix] = f2bf(acc[i][j][r] + bf2f(bias[gc]) + bf2f(xin[ix]));
            }
}

// ---------------- fc1 GEMM + bias + fast GELU -> hmid bf16 -----------------
// 8-wave 128x128, grid flattened to 1536 independent single-tile blocks.
__global__ __launch_bounds__(512) void k_gemm_fc1(const u16* __restrict__ A,
                                                  const u16* __restrict__ W,
                                                  const u16* __restrict__ bias,
                                                  u16* __restrict__ hmid)
{
    const int id = blockIdx.x, slot = id & 7, idx = id >> 3;
    const int m0 = (slot * 16 + idx / 12) * 128;
    const int n0 = (idx % 12) * 128;
    f32x4 acc[4][2];
#pragma unroll
    for (int i = 0; i < 4; i++)
#pragma unroll
        for (int j = 0; j < 2; j++) acc[i][j] = f32x4{0.f, 0.f, 0.f, 0.f};
    gemm_core_128_w8(A, W, 384, m0, n0, acc);
    const int lane = threadIdx.x & 63, wid = threadIdx.x >> 6;
    const int wm = (wid >> 2) * 64, wn = (wid & 3) * 32;
    const int l15 = lane & 15, rq = (lane >> 4) * 4;
#pragma unroll
    for (int i = 0; i < 4; i++)
#pragma unroll
        for (int j = 0; j < 2; j++)
#pragma unroll
            for (int r = 0; r < 4; r++) {
                int gr = m0 + wm + 16 * i + rq + r;
                int gc = n0 + wn + 16 * j + l15;
                float v = acc[i][j][r] + bf2f(bias[gc]);
                float u2 = v * (2.3022084f + 0.1029433f * v * v);
                float ge = v * __builtin_amdgcn_rcpf(
                               1.0f + __ocml_native_exp2_f32(-u2));
                hmid[(size_t)gr * 1536 + gc] = f2bf(ge);
            }
}

// ---------------- fc2 GEMM + bias + residual(x1 bf16) -> out ---------------
__global__ __launch_bounds__(512) void k_gemm_fc2(const u16* __restrict__ A,
                                                  const u16* __restrict__ W,
                                                  const u16* __restrict__ bias,
                                                  const u16* __restrict__ x1,
                                                  void* __restrict__ outv,
                                                  const int* __restrict__ flagp)
{
    const int id = blockIdx.x, slot = id & 7, idx = id >> 3;
    const int m0 = (slot * 16 + idx / 6) * 128;
    const int n0 = (idx % 6) * 64;
    f32x4 acc[2][2];
#pragma unroll
    for (int i = 0; i < 2; i++)
#pragma unroll
        for (int j = 0; j < 2; j++) acc[i][j] = f32x4{0.f, 0.f, 0.f, 0.f};
    gemm_core_128x64_w8(A, W, 1536, m0, n0, acc);
    const int lane = threadIdx.x & 63, wid = threadIdx.x >> 6;
    const int wm = (wid >> 1) * 32, wn = (wid & 1) * 32;
    const int l15 = lane & 15, rq = (lane >> 4) * 4;
    const int isbf = *flagp;
    u16*   ob = (u16*)outv;
    float* of = (float*)outv;
#pragma unroll
    for (int i = 0; i < 2; i++)
#pragma unroll
        for (int j = 0; j < 2; j++)
#pragma unroll
            for (int r = 0; r < 4; r++) {
                int gr = m0 + wm + 16 * i + rq + r;
                int gc = n0 + wn + 16 * j + l15;
                size_t ix = (size_t)gr * 384 + gc;
                float v = acc[i][j][r] + bf2f(bias[gc]) + bf2f(x1[ix]);
                if (isbf) ob[ix] = f2bf(v);
                else      of[ix] = v;
            }
}

// ---------------------------------------------------------------------------
extern "C" void kernel_launch(void* const* d_in, const int* in_sizes, int n_in,
                              void* d_out, int out_size, void* d_ws, size_t ws_size,
                              hipStream_t stream)
{
    char* ws = (char*)d_ws;
    u16*   cw   = (u16*)(ws + 0);            // 3,548,928
    int*   flag = (int*)(ws + 3548928);      // 256
    u16*   cx   = (u16*)(ws + 3549184);      // 12,582,912
    u16*   h    = (u16*)(ws + 16132096);     // 12,582,912
    u16*   x1   = (u16*)(ws + 28715008);     // 12,582,912 (bf16)
    u16*   q    = (u16*)(ws + 53880832);     // 12,582,912
    u16*   kbuf = (u16*)(ws + 66463744);     // 12,582,912
    u16*   vT   = (u16*)(ws + 79046656);     // 12,582,912
    u16*   o    = (u16*)(ws + 91629568);     // 12,582,912 (ends 104,212,480)
    u16*   hmid = (u16*)(ws + 53880832);     // 50,331,648 aliases q..o (dead in MLP)

    const u16* c_qkv_w  = cw + 768;
    const u16* c_qkv_b  = cw + 443136;
    const u16* c_proj_w = cw + 444288;
    const u16* c_proj_b = cw + 591744;
    const u16* c_ln2_g  = cw + 592128;
    const u16* c_ln2_b  = cw + 592512;
    const u16* c_fc1_w  = cw + 592896;
    const u16* c_fc1_b  = cw + 1182720;
    const u16* c_fc2_w  = cw + 1184256;
    const u16* c_fc2_b  = cw + 1774080;

    Ptrs ps;
    for (int i = 0; i < 13; ++i) ps.p[i] = d_in[i];

    k_cvt_ln1<<<4963, 256, 0, stream>>>(ps, cw, flag, cx, h);
    k_gemm_qkv<<<1152, 512, 0, stream>>>(h, c_qkv_w, c_qkv_b, q, kbuf, vT);
    k_attn<<<768, 512, 0, stream>>>(q, kbuf, vT, o);
    k_gemm_proj<<<768, 512, 0, stream>>>(o, c_proj_w, c_proj_b, cx, x1);
    k_layernorm<<<4096, 256, 0, stream>>>(x1, c_ln2_g, c_ln2_b, h, 16384);
    k_gemm_fc1<<<1536, 512, 0, stream>>>(h, c_fc1_w, c_fc1_b, hmid);
    k_gemm_fc2<<<768, 512, 0, stream>>>(hmid, c_fc2_w, c_fc2_b, x1,
                                        d_out, flag);
    (void)in_sizes; (void)n_in; (void)out_size; (void)ws_size; (void)c_fc2_b;
}

// Round 14
// 231.325 us; speedup vs baseline: 1.0481x; 1.0481x over previous
//
#include <hip/hip_runtime.h>

typedef unsigned short u16;
typedef unsigned int   u32;
typedef __bf16  bf16x8 __attribute__((ext_vector_type(8)));
typedef __bf16  bf16x4_t __attribute__((ext_vector_type(4)));
typedef float   f32x4  __attribute__((ext_vector_type(4)));
typedef float   f32x2  __attribute__((ext_vector_type(2)));

struct Ptrs { const void* p[13]; };

extern "C" __device__ float __ocml_native_exp2_f32(float);  // -> v_exp_f32

// ---------- bf16 <-> f32 helpers ----------
__device__ __forceinline__ float bf2f(u16 u) {
    union { unsigned int i; float f; } c; c.i = ((unsigned int)u) << 16; return c.f;
}
__device__ __forceinline__ u16 f2bf(float f) {
    union { float f; unsigned int i; } c; c.f = f;
    unsigned int u = c.i;
    unsigned int r = (u + 0x7fffu + ((u >> 16) & 1u)) >> 16;  // RNE
    return (u16)r;
}

__device__ __forceinline__ float wave_sum(float x) {
#pragma unroll
    for (int m = 32; m >= 1; m >>= 1) x += __shfl_xor(x, m);
    return x;
}

// async global->LDS 16B/lane. LDS dest is wave-uniform base + lane*16.
__device__ __forceinline__ void g2l16(const u16* g, u16* l) {
    __builtin_amdgcn_global_load_lds(
        (__attribute__((address_space(1))) void*)g,
        (__attribute__((address_space(3))) void*)l, 16, 0, 0);
}

// dtype sniff: 32 dwords of qkv_w (bf16 low-half exponent distribution).
__device__ __forceinline__ int sniff_bf16(const u32* __restrict__ w) {
    int cnt = 0;
    for (int i = 0; i < 32; ++i) {
        u16 lo = (u16)(w[i] & 0xFFFFu);
        int e = (lo >> 7) & 0xFF;
        cnt += (e >= 117 && e <= 123) ? 1 : 0;
    }
    return (cnt >= 16) ? 1 : 0;
}

// ---------------------------------------------------------------------------
// Fused: weight canonicalization (blocks < 867) + x-conversion/LN1 (rest).
// ---------------------------------------------------------------------------
__global__ __launch_bounds__(256) void k_cvt_ln1(Ptrs ps,
                                                 u16* __restrict__ cw,
                                                 int* __restrict__ flagp,
                                                 u16* __restrict__ cx,
                                                 u16* __restrict__ h)
{
    const int flag = sniff_bf16((const u32*)ps.p[3]);
    if (blockIdx.x == 0 && threadIdx.x == 0) *flagp = flag;

    if (blockIdx.x < 867) {
        // ---- weight conversion path ----
        const int cum[13] = {0,48,96,55392,55536,73968,74016,74064,74112,
                             147840,148032,221760,221808};
        const int off[12] = {0,384,768,443136,444288,591744,
                             592128,592512,592896,1182720,1184256,1774080};
        int c = blockIdx.x * 256 + threadIdx.x;
        if (c >= 221808) return;
        int seg = 0;
#pragma unroll
        for (int i = 1; i < 12; ++i) seg += (c >= cum[i]) ? 1 : 0;
        int e = (c - cum[seg]) * 8;
        u16* dst = cw + off[seg] + e;
        if (flag) {
            *(uint4*)dst = *((const uint4*)ps.p[seg + 1] + (e >> 3));
        } else {
            const float* s = (const float*)ps.p[seg + 1] + e;
            u16 tmp[8];
#pragma unroll
            for (int t = 0; t < 8; ++t) tmp[t] = f2bf(s[t]);
            *(uint4*)dst = *(const uint4*)tmp;
        }
        return;
    }

    // ---- LN1 + x-canonicalization path ----
    const int wid = threadIdx.x >> 6, lane = threadIdx.x & 63;
    const int row = (blockIdx.x - 867) * 4 + wid;
    const int e0 = lane * 6;
    float v[6]; u16 raw[6];
    float gv[6], bv[6];
    if (flag) {
        const u16* p = (const u16*)ps.p[0] + (size_t)row * 384 + e0;
        u32 w0 = *(const u32*)(p);
        u32 w1 = *(const u32*)(p + 2);
        u32 w2 = *(const u32*)(p + 4);
        raw[0] = (u16)w0; raw[1] = (u16)(w0 >> 16);
        raw[2] = (u16)w1; raw[3] = (u16)(w1 >> 16);
        raw[4] = (u16)w2; raw[5] = (u16)(w2 >> 16);
#pragma unroll
        for (int t = 0; t < 6; t++) v[t] = bf2f(raw[t]);
        const u16* gp = (const u16*)ps.p[1] + e0;
        const u16* bp = (const u16*)ps.p[2] + e0;
#pragma unroll
        for (int t = 0; t < 6; t++) { gv[t] = bf2f(gp[t]); bv[t] = bf2f(bp[t]); }
    } else {
        const float* p = (const float*)ps.p[0] + (size_t)row * 384 + e0;
        f32x2 a0 = *(const f32x2*)(p);
        f32x2 a1 = *(const f32x2*)(p + 2);
        f32x2 a2 = *(const f32x2*)(p + 4);
        v[0] = a0[0]; v[1] = a0[1]; v[2] = a1[0];
        v[3] = a1[1]; v[4] = a2[0]; v[5] = a2[1];
#pragma unroll
        for (int t = 0; t < 6; t++) raw[t] = f2bf(v[t]);
        const float* gp = (const float*)ps.p[1] + e0;
        const float* bp = (const float*)ps.p[2] + e0;
#pragma unroll
        for (int t = 0; t < 6; t++) { gv[t] = gp[t]; bv[t] = bp[t]; }
    }
    u32* pc = (u32*)(cx + (size_t)row * 384 + e0);
    pc[0] = (u32)raw[0] | ((u32)raw[1] << 16);
    pc[1] = (u32)raw[2] | ((u32)raw[3] << 16);
    pc[2] = (u32)raw[4] | ((u32)raw[5] << 16);
    float s = 0.f;
#pragma unroll
    for (int t = 0; t < 6; t++) s += v[t];
    const float mu = wave_sum(s) * (1.0f / 384.0f);
    float vs = 0.f;
#pragma unroll
    for (int t = 0; t < 6; t++) { float d = v[t] - mu; vs += d * d; }
    const float var = wave_sum(vs) * (1.0f / 384.0f);
    const float rs = rsqrtf(var + 1e-5f);
    u16 ow[6];
#pragma unroll
    for (int t = 0; t < 6; t++)
        ow[t] = f2bf((v[t] - mu) * rs * gv[t] + bv[t]);
    u32* po = (u32*)(h + (size_t)row * 384 + e0);
    po[0] = (u32)ow[0] | ((u32)ow[1] << 16);
    po[1] = (u32)ow[2] | ((u32)ow[3] << 16);
    po[2] = (u32)ow[4] | ((u32)ow[5] << 16);
}

// ---------------------------------------------------------------------------
// Core MFMA GEMM 128x128, 8-WAVE version (512 threads): each wave owns
// 64x32 (acc[4][2] = 32 VGPR). Full 2048-thread/CU occupancy.
// SWAP=true swaps mfma operand order (quad axis = B-row).
// ---------------------------------------------------------------------------
template <bool SWAP = false>
__device__ __forceinline__ void gemm_core_128_w8(const u16* __restrict__ A,
                                                 const u16* __restrict__ B,
                                                 int K, int m0, int n0,
                                                 f32x4 (&acc)[4][2])
{
    __shared__ __align__(16) u16 As[128 * 64];
    __shared__ __align__(16) u16 Bs[128 * 64];

    const int tid  = threadIdx.x;
    const int lane = tid & 63;
    const int wid  = tid >> 6;           // 0..7
    const int wm  = (wid >> 2) * 64;     // 0, 64
    const int wn  = (wid & 3) * 32;      // 0, 32, 64, 96
    const int l15 = lane & 15;
    const int g   = lane >> 4;
    const int srow   = lane >> 3;
    const int schunk = ((lane & 7) ^ srow) * 8;

    const u16* Abase = A + (size_t)(m0 + wid * 16 + srow) * K + schunk;
    const u16* Bbase = B + (size_t)(n0 + wid * 16 + srow) * K + schunk;

    for (int kk = 0; kk < K; kk += 64) {
        __syncthreads();
#pragma unroll
        for (int t = 0; t < 2; ++t) {
            g2l16(Abase + (size_t)t * 8 * K + kk, &As[(wid * 16 + t * 8) * 64]);
            g2l16(Bbase + (size_t)t * 8 * K + kk, &Bs[(wid * 16 + t * 8) * 64]);
        }
        __syncthreads();

#pragma unroll
        for (int ks = 0; ks < 2; ++ks) {
            const int p = ((ks * 4 + g) ^ (l15 & 7)) * 8;
            bf16x8 af[4], bfr[2];
#pragma unroll
            for (int i = 0; i < 4; i++)
                af[i] = __builtin_bit_cast(bf16x8,
                         *(const uint4*)&As[(wm + 16 * i + l15) * 64 + p]);
#pragma unroll
            for (int j = 0; j < 2; j++)
                bfr[j] = __builtin_bit_cast(bf16x8,
                         *(const uint4*)&Bs[(wn + 16 * j + l15) * 64 + p]);
#pragma unroll
            for (int i = 0; i < 4; i++)
#pragma unroll
                for (int j = 0; j < 2; j++) {
                    if (SWAP)
                        acc[i][j] = __builtin_amdgcn_mfma_f32_16x16x32_bf16(
                                        bfr[j], af[i], acc[i][j], 0, 0, 0);
                    else
                        acc[i][j] = __builtin_amdgcn_mfma_f32_16x16x32_bf16(
                                        af[i], bfr[j], acc[i][j], 0, 0, 0);
                }
        }
    }
}

// ---------------------------------------------------------------------------
// Core MFMA GEMM 128x64, 8-WAVE version (512 threads): per-wave 32x32,
// acc[2][2] = 16 VGPR. LDS 24 KB.
// ---------------------------------------------------------------------------
__device__ __forceinline__ void gemm_core_128x64_w8(const u16* __restrict__ A,
                                                    const u16* __restrict__ B,
                                                    int K, int m0, int n0,
                                                    f32x4 (&acc)[2][2])
{
    __shared__ __align__(16) u16 As[128 * 64];
    __shared__ __align__(16) u16 Bs[64 * 64];

    const int tid  = threadIdx.x;
    const int lane = tid & 63;
    const int wid  = tid >> 6;           // 0..7
    const int wm  = (wid >> 1) * 32;     // 0,32,64,96
    const int wn  = (wid & 1) * 32;      // 0,32
    const int l15 = lane & 15;
    const int g   = lane >> 4;
    const int srow   = lane >> 3;
    const int schunk = ((lane & 7) ^ srow) * 8;

    const u16* Abase = A + (size_t)(m0 + wid * 16 + srow) * K + schunk;
    const u16* Bbase = B + (size_t)(n0 + wid * 8 + srow) * K + schunk;

    for (int kk = 0; kk < K; kk += 64) {
        __syncthreads();
#pragma unroll
        for (int t = 0; t < 2; ++t)
            g2l16(Abase + (size_t)t * 8 * K + kk, &As[(wid * 16 + t * 8) * 64]);
        g2l16(Bbase + kk, &Bs[(wid * 8) * 64]);
        __syncthreads();

#pragma unroll
        for (int ks = 0; ks < 2; ++ks) {
            const int p = ((ks * 4 + g) ^ (l15 & 7)) * 8;
            bf16x8 af[2], bfr[2];
#pragma unroll
            for (int i = 0; i < 2; i++)
                af[i] = __builtin_bit_cast(bf16x8,
                         *(const uint4*)&As[(wm + 16 * i + l15) * 64 + p]);
#pragma unroll
            for (int j = 0; j < 2; j++)
                bfr[j] = __builtin_bit_cast(bf16x8,
                         *(const uint4*)&Bs[(wn + 16 * j + l15) * 64 + p]);
#pragma unroll
            for (int i = 0; i < 2; i++)
#pragma unroll
                for (int j = 0; j < 2; j++)
                    acc[i][j] = __builtin_amdgcn_mfma_f32_16x16x32_bf16(
                                    af[i], bfr[j], acc[i][j], 0, 0, 0);
        }
    }
}

// ---------------- LayerNorm (bf16 in; used for LN2) ----------------
__global__ __launch_bounds__(256) void k_layernorm(const u16* __restrict__ in,
                                                   const u16* __restrict__ g,
                                                   const u16* __restrict__ b,
                                                   u16* __restrict__ out,
                                                   int nrows)
{
    const int wid = threadIdx.x >> 6, lane = threadIdx.x & 63;
    const int row = blockIdx.x * 4 + wid;
    if (row >= nrows) return;
    const int e0 = lane * 6;
    float v[6];
    const u16* p = in + (size_t)row * 384 + e0;
    u32 w0 = *(const u32*)(p);
    u32 w1 = *(const u32*)(p + 2);
    u32 w2 = *(const u32*)(p + 4);
    v[0] = bf2f((u16)w0); v[1] = bf2f((u16)(w0 >> 16));
    v[2] = bf2f((u16)w1); v[3] = bf2f((u16)(w1 >> 16));
    v[4] = bf2f((u16)w2); v[5] = bf2f((u16)(w2 >> 16));
    float s = 0.f;
#pragma unroll
    for (int t = 0; t < 6; t++) s += v[t];
    const float mu = wave_sum(s) * (1.0f / 384.0f);
    float vs = 0.f;
#pragma unroll
    for (int t = 0; t < 6; t++) { float d = v[t] - mu; vs += d * d; }
    const float var = wave_sum(vs) * (1.0f / 384.0f);
    const float rs = rsqrtf(var + 1e-5f);
    const u32* gg = (const u32*)(g + e0);
    const u32* bb = (const u32*)(b + e0);
    u32 gw[3] = {gg[0], gg[1], gg[2]};
    u32 bw[3] = {bb[0], bb[1], bb[2]};
    u16 ow[6];
#pragma unroll
    for (int t = 0; t < 6; t++) {
        u16 ge = (u16)(gw[t >> 1] >> ((t & 1) * 16));
        u16 be = (u16)(bw[t >> 1] >> ((t & 1) * 16));
        ow[t] = f2bf((v[t] - mu) * rs * bf2f(ge) + bf2f(be));
    }
    u32* po = (u32*)(out + (size_t)row * 384 + e0);
    po[0] = (u32)ow[0] | ((u32)ow[1] << 16);
    po[1] = (u32)ow[2] | ((u32)ow[3] << 16);
    po[2] = (u32)ow[4] | ((u32)ow[5] << 16);
}

// ---------------- QKV GEMM + bias + scatter; V written TRANSPOSED ----------
// 8-wave SWAP core: reg quad = output COLUMN (dh) axis -> q/k one aligned
// 8B store per (i,j); vT 4x scalar.
__global__ __launch_bounds__(512) void k_gemm_qkv(const u16* __restrict__ A,
                                                  const u16* __restrict__ W,
                                                  const u16* __restrict__ bias,
                                                  u16* __restrict__ q,
                                                  u16* __restrict__ kbuf,
                                                  u16* __restrict__ vT)
{
    const int id = blockIdx.x, slot = id & 7, idx = id >> 3;
    const int m0 = (slot * 16 + idx / 9) * 128;
    const int n0 = (idx % 9) * 128;
    f32x4 acc[4][2];
#pragma unroll
    for (int i = 0; i < 4; i++)
#pragma unroll
        for (int j = 0; j < 2; j++) acc[i][j] = f32x4{0.f, 0.f, 0.f, 0.f};
    gemm_core_128_w8<true>(A, W, 384, m0, n0, acc);
    const int lane = threadIdx.x & 63, wid = threadIdx.x >> 6;
    const int wm = (wid >> 2) * 64, wn = (wid & 3) * 32;
    const int l15 = lane & 15, rq = (lane >> 4) * 4;
#pragma unroll
    for (int i = 0; i < 4; i++) {
        const int gr = m0 + wm + 16 * i + l15;        // row on lane axis
        const int bb = gr >> 10, nn = gr & 1023;
#pragma unroll
        for (int j = 0; j < 2; j++) {
            const int gcb = n0 + wn + 16 * j + rq;    // col base on quad axis
            const int part = gcb / 384, rem = gcb % 384;
            const int head = rem >> 6, dhb = rem & 63;
            const int bh = bb * 6 + head;
            float vals[4];
#pragma unroll
            for (int r = 0; r < 4; r++) vals[r] = acc[i][j][r] + bf2f(bias[gcb + r]);
            if (part == 2) {
#pragma unroll
                for (int r = 0; r < 4; r++)
                    vT[((size_t)bh * 64 + dhb + r) * 1024 + nn] = f2bf(vals[r]);
            } else {
                u16* dst = part ? kbuf : q;
                u32 lo = (u32)f2bf(vals[0]) | ((u32)f2bf(vals[1]) << 16);
                u32 hi = (u32)f2bf(vals[2]) | ((u32)f2bf(vals[3]) << 16);
                uint2 pk; pk.x = lo; pk.y = hi;
                *(uint2*)&dst[((size_t)bh * 1024 + nn) * 64 + dhb] = pk;
            }
        }
    }
}

// ---------------------------------------------------------------------------
// Fused flash attention v7 (verified best, restored): 8 waves of 16 Q-rows,
// 512 threads, g2l16 staging, LDS 48K -> 3 blocks/CU, 24 waves/CU (45%
// occupancy). Three pipeline restructurings all REGRESSED vs this:
//  - T14 reg-stage split (round 11, +7 us): TLP already hides staging.
//  - 64-key double-buffer (round 13, +9.5 us): doubled per-phase overhead.
//  - h-loop unroll (round 4, +12 us): VGPR 128 occupancy cliff.
// This structure is attn's empirical optimum at this problem size.
// ---------------------------------------------------------------------------
__global__ __launch_bounds__(512) void k_attn(const u16* __restrict__ q,
                                              const u16* __restrict__ kk,
                                              const u16* __restrict__ vT,
                                              u16* __restrict__ o)
{
    __shared__ __align__(16) u16 Ks[128 * 64];
    __shared__ __align__(16) u16 Vs[2][64 * 64];
    __shared__ __align__(16) u16 Ps[128 * 64];

    const int tid = threadIdx.x, lane = tid & 63, wid = tid >> 6;  // wid 0..7
    const int l15 = lane & 15, g = lane >> 4, q8 = g * 8;
    const int id = blockIdx.x;
    const int bh = (id & 7) * 12 + ((id >> 3) >> 3);
    const int q0 = ((id >> 3) & 7) * 128;
    const int wrow = wid * 16;                         // 16 rows per wave

    const u16* Q = q  + (size_t)bh * 65536;
    const u16* K = kk + (size_t)bh * 65536;
    const u16* V = vT + (size_t)bh * 65536;

    const int srow   = lane >> 3;
    const int schunk = ((lane & 7) ^ srow) * 8;
    const int rd0 = ((0 + g) ^ (l15 & 7)) * 8;
    const int rd1 = ((4 + g) ^ (l15 & 7)) * 8;
    int pcol[4];
#pragma unroll
    for (int ip = 0; ip < 4; ++ip)
        pcol[ip] = (((ip * 2 + (g >> 1)) ^ (l15 & 7)) * 8) + (g & 1) * 4;

    // Q frags pre-scaled by 0.125*log2(e)
    bf16x8 aq[2];
#pragma unroll
    for (int ks = 0; ks < 2; ++ks) {
        bf16x8 t = __builtin_bit_cast(bf16x8,
            *(const uint4*)&Q[(size_t)(q0 + wrow + l15) * 64 + ks * 32 + q8]);
#pragma unroll
        for (int e = 0; e < 8; ++e)
            t[e] = (__bf16)((float)t[e] * 0.18033688f);
        aq[ks] = t;
    }

    f32x4 ob[4];
#pragma unroll
    for (int j = 0; j < 4; ++j) ob[j] = f32x4{0.f, 0.f, 0.f, 0.f};
    float lsum = 0.f;

    for (int kt2 = 0; kt2 < 8; ++kt2) {
        __syncthreads();
#pragma unroll
        for (int t = 0; t < 2; ++t) {
            int r0 = wid * 16 + t * 8;
            g2l16(&K[(size_t)(kt2 * 128 + r0 + srow) * 64 + schunk], &Ks[r0 * 64]);
        }
#pragma unroll
        for (int h = 0; h < 2; ++h) {
            int r0 = wid * 8;
            g2l16(&V[(size_t)(r0 + srow) * 1024 + kt2 * 128 + h * 64 + schunk],
                  &Vs[h][r0 * 64]);
        }
        __syncthreads();

#pragma unroll 1
        for (int h = 0; h < 2; ++h) {
            f32x4 st[4];
#pragma unroll
            for (int ip = 0; ip < 4; ++ip) st[ip] = f32x4{0.f, 0.f, 0.f, 0.f};
            __builtin_amdgcn_s_setprio(1);
#pragma unroll
            for (int ip = 0; ip < 4; ++ip) {
                int rbase = (h * 64 + ip * 16 + l15) * 64;
                bf16x8 bk0 = __builtin_bit_cast(bf16x8,
                    *(const uint4*)&Ks[rbase + rd0]);
                bf16x8 bk1 = __builtin_bit_cast(bf16x8,
                    *(const uint4*)&Ks[rbase + rd1]);
                st[ip] = __builtin_amdgcn_mfma_f32_16x16x32_bf16(
                            bk0, aq[0], st[ip], 0, 0, 0);
                st[ip] = __builtin_amdgcn_mfma_f32_16x16x32_bf16(
                            bk1, aq[1], st[ip], 0, 0, 0);
            }
            __builtin_amdgcn_s_setprio(0);

            // P = 2^S' (single v_exp_f32), lane-local row sums
            float ps = 0.f;
#pragma unroll
            for (int ip = 0; ip < 4; ++ip)
#pragma unroll
                for (int r = 0; r < 4; ++r) {
                    float p = __ocml_native_exp2_f32(st[ip][r]);
                    st[ip][r] = p;
                    ps += p;
                }
            lsum += ps;

            // P -> Ps (pair-swizzled), wave-private rows, no barrier
#pragma unroll
            for (int ip = 0; ip < 4; ++ip) {
                bf16x4_t pk;
#pragma unroll
                for (int r = 0; r < 4; ++r) pk[r] = (__bf16)st[ip][r];
                *(bf16x4_t*)&Ps[(wrow + l15) * 64 + pcol[ip]] = pk;
            }

            // O += P @ V_half
            __builtin_amdgcn_s_setprio(1);
#pragma unroll
            for (int ks = 0; ks < 2; ++ks) {
                const int rdo = ks ? rd1 : rd0;
                bf16x8 ap = __builtin_bit_cast(bf16x8,
                    *(const uint4*)&Ps[(wrow + l15) * 64 + rdo]);
#pragma unroll
                for (int jv = 0; jv < 4; ++jv) {
                    bf16x8 bv = __builtin_bit_cast(bf16x8,
                        *(const uint4*)&Vs[h][(jv * 16 + l15) * 64 + rdo]);
                    ob[jv] = __builtin_amdgcn_mfma_f32_16x16x32_bf16(
                                ap, bv, ob[jv], 0, 0, 0);
                }
            }
            __builtin_amdgcn_s_setprio(0);
        }
    }

    lsum += __shfl_xor(lsum, 16);
    lsum += __shfl_xor(lsum, 32);
    const int bb = bh / 6, hh = bh % 6;
#pragma unroll
    for (int r = 0; r < 4; ++r) {
        int src = (lane & 48) | (g * 4 + r);
        float linv = 1.0f / __shfl(lsum, src);
        int row = q0 + wrow + g * 4 + r;
#pragma unroll
        for (int jv = 0; jv < 4; ++jv) {
            int dh = jv * 16 + l15;
            o[((size_t)(bb * 1024 + row)) * 384 + hh * 64 + dh] =
                f2bf(ob[jv][r] * linv);
        }
    }
}

// ---------------- proj GEMM + bias + residual(cx) -> x1 bf16 ---------------
__global__ __launch_bounds__(512) void k_gemm_proj(const u16* __restrict__ A,
                                                   const u16* __restrict__ W,
                                                   const u16* __restrict__ bias,
                                                   const u16* __restrict__ xin,
                                                   u16* __restrict__ x1)
{
    const int id = blockIdx.x, slot = id & 7, idx = id >> 3;
    const int m0 = (slot * 16 + idx / 6) * 128;
    const int n0 = (idx % 6) * 64;
    f32x4 acc[2][2];
#pragma unroll
    for (int i = 0; i < 2; i++)
#pragma unroll
        for (int j = 0; j < 2; j++) acc[i][j] = f32x4{0.f, 0.f, 0.f, 0.f};
    gemm_core_128x64_w8(A, W, 384, m0, n0, acc);
    const int lane = threadIdx.x & 63, wid = threadIdx.x >> 6;
    const int wm = (wid >> 1) * 32, wn = (wid & 1) * 32;
    const int l15 = lane & 15, rq = (lane >> 4) * 4;
#pragma unroll
    for (int i = 0; i < 2; i++)
#pragma unroll
        for (int j = 0; j < 2; j++)
#pragma unroll
            for (int r = 0; r < 4; r++) {
                int gr = m0 + wm + 16 * i + rq + r;
                int gc = n0 + wn + 16 * j + l15;
                size_t ix = (size_t)gr * 384 + gc;
                x1[ix] = f2bf(acc[i][j][r] + bf2f(bias[gc]) + bf2f(xin[ix]));
            }
}

// ---------------- fc1 GEMM + bias + fast GELU -> hmid bf16 -----------------
// 8-wave 128x128, grid flattened to 1536 independent single-tile blocks.
__global__ __launch_bounds__(512) void k_gemm_fc1(const u16* __restrict__ A,
                                                  const u16* __restrict__ W,
                                                  const u16* __restrict__ bias,
                                                  u16* __restrict__ hmid)
{
    const int id = blockIdx.x, slot = id & 7, idx = id >> 3;
    const int m0 = (slot * 16 + idx / 12) * 128;
    const int n0 = (idx % 12) * 128;
    f32x4 acc[4][2];
#pragma unroll
    for (int i = 0; i < 4; i++)
#pragma unroll
        for (int j = 0; j < 2; j++) acc[i][j] = f32x4{0.f, 0.f, 0.f, 0.f};
    gemm_core_128_w8(A, W, 384, m0, n0, acc);
    const int lane = threadIdx.x & 63, wid = threadIdx.x >> 6;
    const int wm = (wid >> 2) * 64, wn = (wid & 3) * 32;
    const int l15 = lane & 15, rq = (lane >> 4) * 4;
#pragma unroll
    for (int i = 0; i < 4; i++)
#pragma unroll
        for (int j = 0; j < 2; j++)
#pragma unroll
            for (int r = 0; r < 4; r++) {
                int gr = m0 + wm + 16 * i + rq + r;
                int gc = n0 + wn + 16 * j + l15;
                float v = acc[i][j][r] + bf2f(bias[gc]);
                float u2 = v * (2.3022084f + 0.1029433f * v * v);
                float ge = v * __builtin_amdgcn_rcpf(
                               1.0f + __ocml_native_exp2_f32(-u2));
                hmid[(size_t)gr * 1536 + gc] = f2bf(ge);
            }
}

// ---------------- fc2 GEMM + bias + residual(x1 bf16) -> out ---------------
__global__ __launch_bounds__(512) void k_gemm_fc2(const u16* __restrict__ A,
                                                  const u16* __restrict__ W,
                                                  const u16* __restrict__ bias,
                                                  const u16* __restrict__ x1,
                                                  void* __restrict__ outv,
                                                  const int* __restrict__ flagp)
{
    const int id = blockIdx.x, slot = id & 7, idx = id >> 3;
    const int m0 = (slot * 16 + idx / 6) * 128;
    const int n0 = (idx % 6) * 64;
    f32x4 acc[2][2];
#pragma unroll
    for (int i = 0; i < 2; i++)
#pragma unroll
        for (int j = 0; j < 2; j++) acc[i][j] = f32x4{0.f, 0.f, 0.f, 0.f};
    gemm_core_128x64_w8(A, W, 1536, m0, n0, acc);
    const int lane = threadIdx.x & 63, wid = threadIdx.x >> 6;
    const int wm = (wid >> 1) * 32, wn = (wid & 1) * 32;
    const int l15 = lane & 15, rq = (lane >> 4) * 4;
    const int isbf = *flagp;
    u16*   ob = (u16*)outv;
    float* of = (float*)outv;
#pragma unroll
    for (int i = 0; i < 2; i++)
#pragma unroll
        for (int j = 0; j < 2; j++)
#pragma unroll
            for (int r = 0; r < 4; r++) {
                int gr = m0 + wm + 16 * i + rq + r;
                int gc = n0 + wn + 16 * j + l15;
                size_t ix = (size_t)gr * 384 + gc;
                float v = acc[i][j][r] + bf2f(bias[gc]) + bf2f(x1[ix]);
                if (isbf) ob[ix] = f2bf(v);
                else      of[ix] = v;
            }
}

// ---------------------------------------------------------------------------
extern "C" void kernel_launch(void* const* d_in, const int* in_sizes, int n_in,
                              void* d_out, int out_size, void* d_ws, size_t ws_size,
                              hipStream_t stream)
{
    char* ws = (char*)d_ws;
    u16*   cw   = (u16*)(ws + 0);            // 3,548,928
    int*   flag = (int*)(ws + 3548928);      // 256
    u16*   cx   = (u16*)(ws + 3549184);      // 12,582,912
    u16*   h    = (u16*)(ws + 16132096);     // 12,582,912
    u16*   x1   = (u16*)(ws + 28715008);     // 12,582,912 (bf16)
    u16*   q    = (u16*)(ws + 53880832);     // 12,582,912
    u16*   kbuf = (u16*)(ws + 66463744);     // 12,582,912
    u16*   vT   = (u16*)(ws + 79046656);     // 12,582,912
    u16*   o    = (u16*)(ws + 91629568);     // 12,582,912 (ends 104,212,480)
    u16*   hmid = (u16*)(ws + 53880832);     // 50,331,648 aliases q..o (dead in MLP)

    const u16* c_qkv_w  = cw + 768;
    const u16* c_qkv_b  = cw + 443136;
    const u16* c_proj_w = cw + 444288;
    const u16* c_proj_b = cw + 591744;
    const u16* c_ln2_g  = cw + 592128;
    const u16* c_ln2_b  = cw + 592512;
    const u16* c_fc1_w  = cw + 592896;
    const u16* c_fc1_b  = cw + 1182720;
    const u16* c_fc2_w  = cw + 1184256;
    const u16* c_fc2_b  = cw + 1774080;

    Ptrs ps;
    for (int i = 0; i < 13; ++i) ps.p[i] = d_in[i];

    k_cvt_ln1<<<4963, 256, 0, stream>>>(ps, cw, flag, cx, h);
    k_gemm_qkv<<<1152, 512, 0, stream>>>(h, c_qkv_w, c_qkv_b, q, kbuf, vT);
    k_attn<<<768, 512, 0, stream>>>(q, kbuf, vT, o);
    k_gemm_proj<<<768, 512, 0, stream>>>(o, c_proj_w, c_proj_b, cx, x1);
    k_layernorm<<<4096, 256, 0, stream>>>(x1, c_ln2_g, c_ln2_b, h, 16384);
    k_gemm_fc1<<<1536, 512, 0, stream>>>(h, c_fc1_w, c_fc1_b, hmid);
    k_gemm_fc2<<<768, 512, 0, stream>>>(hmid, c_fc2_w, c_fc2_b, x1,
                                        d_out, flag);
    (void)in_sizes; (void)n_in; (void)out_size; (void)ws_size; (void)c_fc2_b;
}